// Round 1
// baseline (23039.720 us; speedup 1.0000x reference)
//
#include <hip/hip_runtime.h>

// Problem constants (from reference): N=1024, K=32, F=8192, E=64, H1=128, H2=64, T=3

// ---------------------------------------------------------------------------
// K1: G0 = X @ W_emb  (f64 accumulation), feat0 = relu(G0 + b_emb), out=feat0
// grid 256 x 256 threads; block handles 4 nodes; thread -> (node, output j)
// ---------------------------------------------------------------------------
__global__ __launch_bounds__(256) void k_embed(
    const float* __restrict__ X, const float* __restrict__ W_emb,
    const float* __restrict__ b_emb,
    float* __restrict__ G0, float* __restrict__ feat0, float* __restrict__ out)
{
  const int t = threadIdx.x;
  const int j = t & 63;                       // output column 0..63
  const int node = (blockIdx.x << 2) + (t >> 6);
  const float* __restrict__ xr = X + (size_t)node * 8192;
  const float* __restrict__ wp = W_emb + j;
  double a0 = 0.0, a1 = 0.0, a2 = 0.0, a3 = 0.0;
  for (int f = 0; f < 8192; f += 4) {
    float x0 = xr[f + 0], x1 = xr[f + 1], x2 = xr[f + 2], x3 = xr[f + 3];
    a0 = fma((double)x0, (double)wp[(f + 0) << 6], a0);
    a1 = fma((double)x1, (double)wp[(f + 1) << 6], a1);
    a2 = fma((double)x2, (double)wp[(f + 2) << 6], a2);
    a3 = fma((double)x3, (double)wp[(f + 3) << 6], a3);
  }
  float g = (float)((a0 + a1) + (a2 + a3));
  const int o = node * 64 + j;
  G0[o] = g;
  float f0 = fmaxf(g + b_emb[j], 0.0f);
  feat0[o] = f0;
  out[o] = f0;                                 // feature starts as feat0
}

// ---------------------------------------------------------------------------
// K2: Y0 = feat0 @ W1b  (W1 rows 64..127);  Y = Y0 (working copy)
// ---------------------------------------------------------------------------
__global__ __launch_bounds__(128) void k_y0(
    const float* __restrict__ feat0, const float* __restrict__ W1,
    float* __restrict__ Y0, float* __restrict__ Y)
{
  const int c = threadIdx.x;
  const int i = blockIdx.x;
  const float* __restrict__ fr = feat0 + i * 64;
  float acc = 0.0f;
  #pragma unroll 8
  for (int e = 0; e < 64; ++e)
    acc = fmaf(fr[e], W1[(64 + e) * 128 + c], acc);
  Y0[i * 128 + c] = acc;
  Y[i * 128 + c] = acc;
}

// ---------------------------------------------------------------------------
// K3: the serial chain. One workgroup, 512 threads (8 waves), persistent over
// 1024 nodes x 3 steps. W2 held in registers (lane = output column j).
// ---------------------------------------------------------------------------
__global__ __launch_bounds__(512, 2) void k_serial(
    const int* __restrict__ neighbors,
    const float* __restrict__ W1, const float* __restrict__ b1,
    const float* __restrict__ W2, const float* __restrict__ b2,
    const float* __restrict__ W_lk, const float* __restrict__ b_lk,
    const float* __restrict__ W_act, const float* __restrict__ b_act,
    const float* __restrict__ b_emb,
    const float* __restrict__ G0, const float* __restrict__ feat0,
    const float* __restrict__ Y0, float* __restrict__ Y,
    float* __restrict__ feature)   // feature == d_out
{
  __shared__ float h1s[33][128];
  __shared__ float h2s[33][64];
  __shared__ float a1s[128];
  __shared__ float fis[64], gis[64], sumg[64];
  __shared__ float b1s[128], b2s[64], bembs[64], wlks[64], wacts[128];
  __shared__ float lks[36];
  __shared__ int idxs[32];
  __shared__ int s_u, s_upd, s_done;
  __shared__ unsigned s_valid;
  __shared__ float s_take, s_denom, s_cnt;

  const int t = threadIdx.x;
  const int lane = t & 63;
  const int wave = t >> 6;

  // ---- one-time weight preload ----
  if (t < 128) b1s[t] = b1[t];
  if (t < 64) { b2s[t] = b2[t]; bembs[t] = b_emb[t]; wlks[t] = W_lk[t]; }
  if (t < 128) wacts[t] = W_act[t];
  const float blkv = b_lk[0];
  const float ba0 = b_act[0];
  const float ba1 = b_act[1];
  float w2r[128];                       // W2[c][lane], c = 0..127
  #pragma unroll
  for (int c = 0; c < 128; ++c) w2r[c] = W2[c * 64 + lane];
  __syncthreads();

  for (int i = 0; i < 1024; ++i) {
    // ---- node init ----
    if (t < 64) {
      fis[t]  = feature[i * 64 + t];
      gis[t]  = G0[i * 64 + t];
      sumg[t] = 0.0f;
    }
    if (t < 32) idxs[t] = neighbors[i * 32 + t];
    if (t == 0) { s_valid = 0xFFFFFFFFu; s_cnt = 0.0f; s_done = 0; }
    __syncthreads();
    // a1 = fi @ W1a + b1   (first step; later steps produce it in phase E)
    if (t < 128) {
      float aa0 = b1s[t], aa1 = 0.0f;
      #pragma unroll 8
      for (int e = 0; e < 64; e += 2) {
        aa0 = fmaf(fis[e],     W1[e * 128 + t],       aa0);
        aa1 = fmaf(fis[e + 1], W1[(e + 1) * 128 + t], aa1);
      }
      a1s[t] = aa0 + aa1;
    }
    __syncthreads();

    for (int st = 0; st < 3; ++st) {
      // ---- B1: h1[k] = relu(a1 + (idx>0 ? Y[idx[k]] : 0)), k==32 -> relu(a1)
      {
        const int kk = t >> 5;
        const int c4 = (t & 31) << 2;
        #pragma unroll
        for (int kb = 0; kb < 48; kb += 16) {
          int k = kb + kk;
          if (k <= 32) {
            float4 av = *(const float4*)&a1s[c4];
            float yx = 0.f, yy = 0.f, yz = 0.f, yw = 0.f;
            if (k < 32) {
              int v = idxs[k];
              if (v > 0) {
                float4 yv = *(const float4*)&Y[v * 128 + c4];
                yx = yv.x; yy = yv.y; yz = yv.z; yw = yv.w;
              }
            }
            float4 r;
            r.x = fmaxf(av.x + yx, 0.f);
            r.y = fmaxf(av.y + yy, 0.f);
            r.z = fmaxf(av.z + yz, 0.f);
            r.w = fmaxf(av.w + yw, 0.f);
            *(float4*)&h1s[k][c4] = r;
          }
        }
      }
      __syncthreads();
      // ---- B2: h2 = relu(h1 @ W2 + b2); lk = h2 @ W_lk + b_lk
      {
        const float b2v = b2s[lane];
        const float wlkv = wlks[lane];
        for (int k = wave; k < 33; k += 8) {
          float acc0 = b2v, acc1 = 0.f, acc2 = 0.f, acc3 = 0.f;
          const float* __restrict__ hrow = &h1s[k][0];
          #pragma unroll
          for (int c = 0; c < 128; c += 4) {
            float4 hv = *(const float4*)&hrow[c];   // wave-uniform broadcast read
            acc0 = fmaf(hv.x, w2r[c + 0], acc0);
            acc1 = fmaf(hv.y, w2r[c + 1], acc1);
            acc2 = fmaf(hv.z, w2r[c + 2], acc2);
            acc3 = fmaf(hv.w, w2r[c + 3], acc3);
          }
          float h2v = fmaxf((acc0 + acc1) + (acc2 + acc3), 0.f);
          h2s[k][lane] = h2v;
          float p = h2v * wlkv;
          #pragma unroll
          for (int off = 32; off; off >>= 1) p += __shfl_down(p, off);
          if (lane == 0) lks[k] = p + blkv;
        }
      }
      __syncthreads();
      // ---- P4: masked argmax (first-max ties), action argmax, scalar state
      if (wave == 0) {
        const unsigned vm = s_valid;
        float v = -__builtin_inff();
        int ki = 64;
        if (lane < 33) {
          bool m = (lane == 32) || ((vm >> lane) & 1u);
          v = m ? lks[lane] : -__builtin_inff();
          ki = lane;
        }
        #pragma unroll
        for (int off = 32; off; off >>= 1) {
          float ov = __shfl_down(v, off);
          int   oi = __shfl_down(ki, off);
          if (ov > v || (ov == v && oi < ki)) { v = ov; ki = oi; }
        }
        const int ut = __shfl(ki, 0);
        const int utc = ut < 31 ? ut : 31;
        float h  = h2s[utc][lane];
        float p0 = h * wacts[lane * 2 + 0];
        float p1 = h * wacts[lane * 2 + 1];
        #pragma unroll
        for (int off = 32; off; off >>= 1) {
          p0 += __shfl_down(p0, off);
          p1 += __shfl_down(p1, off);
        }
        if (lane == 0) {
          float d0 = p0 + ba0, d1 = p1 + ba1;
          int at1 = (d1 > d0) ? 1 : 0;           // argmax over 2, first-max tie
          int newdone = s_done | (ut == 32);
          int upd = newdone ? 0 : 1;
          float take = at1 ? 1.0f : 0.0f;
          s_u = idxs[utc];
          s_upd = upd;
          s_take = take;
          s_denom = s_cnt + take + 1.0f;         // uses cnt BEFORE update
          if (upd) {
            s_valid = vm & ~(1u << utc);
            s_cnt = s_cnt + take;
          }
          s_done = newdone;
        }
      }
      __syncthreads();
      if (!s_upd) break;    // done: no state changes this or any later step
      const int u = s_u;
      // ---- D: new_fi in G-space; feature[i], feature[u] updates
      if (t < 64) {
        const float take = s_take;
        const float gu = G0[u * 64 + t];
        const float ns = sumg[t] + take * gu;
        const float hv = (ns + gis[t]) / s_denom;
        const float nfi = fmaxf(hv + bembs[t], 0.0f);
        sumg[t] = ns;
        const float f0u = feat0[u * 64 + t];
        feature[i * 64 + t] = nfi;               // feature[i] first,
        feature[u * 64 + t] = f0u;               // then feature[u] (wins if u==i)
        fis[t] = (u == i) ? f0u : nfi;
      }
      __syncthreads();
      // ---- E: Y[i] = fi_new @ W1b; Y[u] = Y0[u]; a1 for next step
      if (t < 128) {
        float acc0 = 0.f, acc1 = 0.f;
        float aa0 = b1s[t], aa1 = 0.f;
        #pragma unroll 4
        for (int e = 0; e < 64; e += 2) {
          float f0v = fis[e], f1v = fis[e + 1];
          acc0 = fmaf(f0v, W1[(64 + e) * 128 + t], acc0);
          acc1 = fmaf(f1v, W1[(64 + e + 1) * 128 + t], acc1);
          aa0  = fmaf(f0v, W1[e * 128 + t], aa0);
          aa1  = fmaf(f1v, W1[(e + 1) * 128 + t], aa1);
        }
        Y[i * 128 + t] = acc0 + acc1;            // Y[i] first,
        Y[u * 128 + t] = Y0[u * 128 + t];        // then Y[u] (wins if u==i)
        a1s[t] = aa0 + aa1;
      }
      __syncthreads();
    }
  }
}

// ---------------------------------------------------------------------------
extern "C" void kernel_launch(void* const* d_in, const int* in_sizes, int n_in,
                              void* d_out, int out_size, void* d_ws, size_t ws_size,
                              hipStream_t stream) {
  const float* X     = (const float*)d_in[0];
  const int*   nbr   = (const int*)  d_in[1];
  const float* W_emb = (const float*)d_in[2];
  const float* b_emb = (const float*)d_in[3];
  const float* W1    = (const float*)d_in[4];
  const float* b1    = (const float*)d_in[5];
  const float* W2    = (const float*)d_in[6];
  const float* b2    = (const float*)d_in[7];
  const float* W_lk  = (const float*)d_in[8];
  const float* b_lk  = (const float*)d_in[9];
  const float* W_act = (const float*)d_in[10];
  const float* b_act = (const float*)d_in[11];
  float* out = (float*)d_out;
  float* ws  = (float*)d_ws;
  float* G0    = ws;             // [1024*64]
  float* feat0 = ws + 65536;     // [1024*64]
  float* Y0    = ws + 131072;    // [1024*128]
  float* Y     = ws + 262144;    // [1024*128]

  hipLaunchKernelGGL(k_embed, dim3(256), dim3(256), 0, stream,
                     X, W_emb, b_emb, G0, feat0, out);
  hipLaunchKernelGGL(k_y0, dim3(1024), dim3(128), 0, stream,
                     feat0, W1, Y0, Y);
  hipLaunchKernelGGL(k_serial, dim3(1), dim3(512), 0, stream,
                     nbr, W1, b1, W2, b2, W_lk, b_lk, W_act, b_act, b_emb,
                     G0, feat0, Y0, Y, out);
}